// Round 12
// baseline (285.026 us; speedup 1.0000x reference)
//
#include <hip/hip_runtime.h>
#include <hip/hip_bf16.h>

// ---------------------------------------------------------------------------
// GCN 2-layer + edge dot logits, CSR-pull aggregation.
// agg[d] = dinv[d] * ( sum_{s in in(d)} hs[s] + hs[d] ) + b,  hs = (A@W)*dinv[row]
// Round 12: r7-best pulls/logits (non-persistent, separate col/eid);
// fill uses nontemporal stores (no write-allocate) and is mod-3 interleaved
// with GEMM1 blocks; BM=32 conflict-free GEMM (r11).
// ---------------------------------------------------------------------------

__global__ void cnt_k(const int* __restrict__ dst, int* __restrict__ cnt, int E) {
    int t = blockIdx.x * blockDim.x + threadIdx.x;
    int e = t * 4;
    if (e + 4 <= E) {
        int4 d4 = *reinterpret_cast<const int4*>(dst + e);
        atomicAdd(&cnt[d4.x], 1);
        atomicAdd(&cnt[d4.y], 1);
        atomicAdd(&cnt[d4.z], 1);
        atomicAdd(&cnt[d4.w], 1);
    } else {
        for (int i = e; i < E; i++) atomicAdd(&cnt[dst[i]], 1);
    }
}

__global__ void scan1_k(const int* __restrict__ cnt, int* __restrict__ incl,
                        int* __restrict__ bsum, int N) {
    __shared__ int sh[256];
    int i = blockIdx.x * 256 + threadIdx.x;
    int v = (i < N) ? cnt[i] : 0;
    sh[threadIdx.x] = v;
    __syncthreads();
#pragma unroll
    for (int off = 1; off < 256; off <<= 1) {
        int t = (threadIdx.x >= off) ? sh[threadIdx.x - off] : 0;
        __syncthreads();
        sh[threadIdx.x] += t;
        __syncthreads();
    }
    if (i < N) incl[i] = sh[threadIdx.x];
    if (threadIdx.x == 255) bsum[blockIdx.x] = sh[255];
}

// fused scan2+scan3: every block rescans bsum in LDS, then elementwise writeback.
__global__ __launch_bounds__(256) void scan23_k(const int* __restrict__ cnt,
                                                const int* __restrict__ incl,
                                                const int* __restrict__ bsum,
                                                int* __restrict__ rowptr,
                                                int* __restrict__ cursor,
                                                float* __restrict__ dinv,
                                                int N, int E, int NB) {
    __shared__ int sh[256];
    __shared__ int blockOff;
    int v = (threadIdx.x < NB) ? bsum[threadIdx.x] : 0;
    sh[threadIdx.x] = v;
    __syncthreads();
#pragma unroll
    for (int off = 1; off < 256; off <<= 1) {
        int t = (threadIdx.x >= off) ? sh[threadIdx.x - off] : 0;
        __syncthreads();
        sh[threadIdx.x] += t;
        __syncthreads();
    }
    if (threadIdx.x == blockIdx.x) blockOff = sh[threadIdx.x] - v;  // exclusive
    __syncthreads();
    int i = blockIdx.x * 256 + threadIdx.x;
    if (i < N) {
        int c = cnt[i];
        int excl = incl[i] - c + blockOff;
        rowptr[i] = excl;
        cursor[i] = excl;
        dinv[i] = rsqrtf(1.0f + (float)c);  // +1 self-loop
    }
    if (i == 0) rowptr[N] = E;
}

// ---------------------------------------------------------------------------
// GEMM body, BM=32, BK=16, 256 threads (r11, conflict-free).
// ---------------------------------------------------------------------------
template <int BN, bool RELU>
__device__ __forceinline__ void gemm_body32(const float* __restrict__ A,
                                            const float* __restrict__ W,
                                            const float* __restrict__ dscale,
                                            float* __restrict__ Out, int M,
                                            int row0, float (*As)[36],
                                            float (*Bs)[BN]) {
    constexpr int K = 128, BK = 16;
    constexpr int TN = BN / 16;  // 8 (BN=128) or 4 (BN=64)
    const int tid = threadIdx.x;
    const int tx = tid & 15, ty = tid >> 4;

    float acc[2][TN];
#pragma unroll
    for (int m = 0; m < 2; m++)
#pragma unroll
        for (int n = 0; n < TN; n++) acc[m][n] = 0.0f;

    for (int kt = 0; kt < K; kt += BK) {
        if (tid < 128) {
            int r = tid >> 2;
            int kq = (tid & 3) * 4;
            float4 av = make_float4(0.f, 0.f, 0.f, 0.f);
            int gr = row0 + r;
            if (gr < M)
                av = *reinterpret_cast<const float4*>(A + (size_t)gr * K + kt + kq);
            if (RELU) {
                av.x = fmaxf(av.x, 0.f); av.y = fmaxf(av.y, 0.f);
                av.z = fmaxf(av.z, 0.f); av.w = fmaxf(av.w, 0.f);
            }
            As[kq + 0][r] = av.x; As[kq + 1][r] = av.y;
            As[kq + 2][r] = av.z; As[kq + 3][r] = av.w;
        }
#pragma unroll
        for (int s = 0; s < (BK * BN) / (256 * 4); s++) {
            int f = s * 256 + tid;
            int brow = f / (BN / 4);
            int bcol = (f % (BN / 4)) * 4;
            float4 bv = *reinterpret_cast<const float4*>(W + (size_t)(kt + brow) * BN + bcol);
            *reinterpret_cast<float4*>(&Bs[brow][bcol]) = bv;
        }
        __syncthreads();

#pragma unroll
        for (int k = 0; k < BK; k++) {
            float2 a2 = *reinterpret_cast<const float2*>(&As[k][ty * 2]);
            float a[2] = {a2.x, a2.y};
            float b[TN];
            float4 b0 = *reinterpret_cast<const float4*>(&Bs[k][tx * 4]);
            b[0] = b0.x; b[1] = b0.y; b[2] = b0.z; b[3] = b0.w;
            if (TN == 8) {
                float4 b1 = *reinterpret_cast<const float4*>(&Bs[k][64 + tx * 4]);
                b[4] = b1.x; b[5] = b1.y; b[6] = b1.z; b[7] = b1.w;
            }
#pragma unroll
            for (int m = 0; m < 2; m++)
#pragma unroll
                for (int n = 0; n < TN; n++) acc[m][n] = fmaf(a[m], b[n], acc[m][n]);
        }
        __syncthreads();
    }

#pragma unroll
    for (int m = 0; m < 2; m++) {
        int gr = row0 + ty * 2 + m;
        if (gr < M) {
            float dv = dscale[gr];
            float4 o0 = make_float4(acc[m][0] * dv, acc[m][1] * dv,
                                    acc[m][2] * dv, acc[m][3] * dv);
            *reinterpret_cast<float4*>(Out + (size_t)gr * BN + tx * 4) = o0;
            if (TN == 8) {
                float4 o1 = make_float4(acc[m][4] * dv, acc[m][5] * dv,
                                        acc[m][6] * dv, acc[m][7] * dv);
                *reinterpret_cast<float4*>(Out + (size_t)gr * BN + 64 + tx * 4) = o1;
            }
        }
    }
}

// ---------------------------------------------------------------------------
// FUSED, mod-3 interleaved: blocks with g%3==2 do CSR fill (nontemporal
// scattered stores); others do GEMM1. Interleave overlaps fill latency with
// GEMM compute from t=0 (range-split serialized them).
// ---------------------------------------------------------------------------
__global__ __launch_bounds__(256) void gemm1_fill_k(const float* __restrict__ A,
                                                    const float* __restrict__ W,
                                                    const float* __restrict__ dscale,
                                                    float* __restrict__ Out, int M,
                                                    const int* __restrict__ src,
                                                    const int* __restrict__ dst,
                                                    int* __restrict__ cursor,
                                                    int* __restrict__ col,
                                                    int* __restrict__ eid, int E) {
    __shared__ float As[16][36];
    __shared__ float Bs[16][128];
    int g = (int)blockIdx.x;
    if (g % 3 == 2) {
        // ---- CSR fill branch: 1024 edges per block ----
        int t = (g / 3) * 256 + threadIdx.x;
        int e = t * 4;
        if (e + 4 <= E) {
            int4 s4 = *reinterpret_cast<const int4*>(src + e);
            int4 d4 = *reinterpret_cast<const int4*>(dst + e);
            int p0 = atomicAdd(&cursor[d4.x], 1);
            __builtin_nontemporal_store(s4.x, col + p0);
            __builtin_nontemporal_store(e + 0, eid + p0);
            int p1 = atomicAdd(&cursor[d4.y], 1);
            __builtin_nontemporal_store(s4.y, col + p1);
            __builtin_nontemporal_store(e + 1, eid + p1);
            int p2 = atomicAdd(&cursor[d4.z], 1);
            __builtin_nontemporal_store(s4.z, col + p2);
            __builtin_nontemporal_store(e + 2, eid + p2);
            int p3 = atomicAdd(&cursor[d4.w], 1);
            __builtin_nontemporal_store(s4.w, col + p3);
            __builtin_nontemporal_store(e + 3, eid + p3);
        } else {
            for (int i = e; i < E; i++) {
                int pos = atomicAdd(&cursor[dst[i]], 1);
                __builtin_nontemporal_store(src[i], col + pos);
                __builtin_nontemporal_store(i, eid + pos);
            }
        }
        return;
    }
    int gemmIdx = g - g / 3;  // g%3 in {0,1}: dense index over non-fill blocks
    gemm_body32<128, false>(A, W, dscale, Out, M, gemmIdx * 32, As, Bs);
}

__global__ __launch_bounds__(256) void gemm2_k(const float* __restrict__ A,
                                               const float* __restrict__ W,
                                               const float* __restrict__ dscale,
                                               float* __restrict__ Out, int M) {
    __shared__ float As[16][36];
    __shared__ float Bs[16][64];
    gemm_body32<64, true>(A, W, dscale, Out, M, (int)blockIdx.x * 32, As, Bs);
}

// ---------------------------------------------------------------------------
// pull128 (r7-best): one wave/node, 2 slots x 32 lanes (row = 32 float4).
// ---------------------------------------------------------------------------
__global__ __launch_bounds__(256) void pull128_k(const int* __restrict__ rowptr,
                                                 const int* __restrict__ col,
                                                 const float4* __restrict__ hs4,
                                                 const float* __restrict__ dinv,
                                                 const float4* __restrict__ bias4,
                                                 float4* __restrict__ out4, int N) {
    int v = (int)((blockIdx.x * (size_t)blockDim.x + threadIdx.x) >> 6);
    if (v >= N) return;
    int lane = threadIdx.x & 63;
    int q = lane & 31, slot = lane >> 5;
    int p0 = rowptr[v], p1 = rowptr[v + 1];

    float4 acc = make_float4(0.f, 0.f, 0.f, 0.f);
    if (slot == 0) acc = hs4[(size_t)v * 32 + q];  // self row

    int p = p0;
    for (; p + 8 <= p1; p += 8) {
        int ia = col[p + slot], ib = col[p + 2 + slot];
        int ic = col[p + 4 + slot], id = col[p + 6 + slot];
        float4 a = hs4[(size_t)ia * 32 + q];
        float4 b = hs4[(size_t)ib * 32 + q];
        float4 c = hs4[(size_t)ic * 32 + q];
        float4 d = hs4[(size_t)id * 32 + q];
        acc.x += (a.x + b.x) + (c.x + d.x);
        acc.y += (a.y + b.y) + (c.y + d.y);
        acc.z += (a.z + b.z) + (c.z + d.z);
        acc.w += (a.w + b.w) + (c.w + d.w);
    }
    for (; p + 2 <= p1; p += 2) {
        int ia = col[p + slot];
        float4 a = hs4[(size_t)ia * 32 + q];
        acc.x += a.x; acc.y += a.y; acc.z += a.z; acc.w += a.w;
    }
    if (p < p1 && slot == 0) {
        float4 a = hs4[(size_t)col[p] * 32 + q];
        acc.x += a.x; acc.y += a.y; acc.z += a.z; acc.w += a.w;
    }

    acc.x += __shfl_xor(acc.x, 32);
    acc.y += __shfl_xor(acc.y, 32);
    acc.z += __shfl_xor(acc.z, 32);
    acc.w += __shfl_xor(acc.w, 32);

    if (slot == 0) {
        float dv = dinv[v];
        float4 bv = bias4[q];
        out4[(size_t)v * 32 + q] = make_float4(fmaf(acc.x, dv, bv.x), fmaf(acc.y, dv, bv.y),
                                               fmaf(acc.z, dv, bv.z), fmaf(acc.w, dv, bv.w));
    }
}

// ---------------------------------------------------------------------------
// pull64 (r7-best): one wave/node, 4 slots x 16 lanes (row = 16 float4).
// ---------------------------------------------------------------------------
__global__ __launch_bounds__(256) void pull64_k(const int* __restrict__ rowptr,
                                                const int* __restrict__ col,
                                                const float4* __restrict__ hs4,
                                                const float* __restrict__ dinv,
                                                const float4* __restrict__ bias4,
                                                float4* __restrict__ out4, int N) {
    int v = (int)((blockIdx.x * (size_t)blockDim.x + threadIdx.x) >> 6);
    if (v >= N) return;
    int lane = threadIdx.x & 63;
    int q = lane & 15, slot = lane >> 4;
    int p0 = rowptr[v], p1 = rowptr[v + 1];

    float4 acc = make_float4(0.f, 0.f, 0.f, 0.f);
    if (slot == 0) acc = hs4[(size_t)v * 16 + q];  // self row

    int p = p0;
    for (; p + 8 <= p1; p += 8) {
        int ia = col[p + slot], ib = col[p + 4 + slot];
        float4 a = hs4[(size_t)ia * 16 + q];
        float4 b = hs4[(size_t)ib * 16 + q];
        acc.x += a.x + b.x; acc.y += a.y + b.y;
        acc.z += a.z + b.z; acc.w += a.w + b.w;
    }
    for (; p + 4 <= p1; p += 4) {
        float4 a = hs4[(size_t)col[p + slot] * 16 + q];
        acc.x += a.x; acc.y += a.y; acc.z += a.z; acc.w += a.w;
    }
    int rem = p1 - p;  // 0..3
    if (slot < rem) {
        float4 a = hs4[(size_t)col[p + slot] * 16 + q];
        acc.x += a.x; acc.y += a.y; acc.z += a.z; acc.w += a.w;
    }

#pragma unroll
    for (int off = 16; off <= 32; off <<= 1) {
        acc.x += __shfl_xor(acc.x, off);
        acc.y += __shfl_xor(acc.y, off);
        acc.z += __shfl_xor(acc.z, off);
        acc.w += __shfl_xor(acc.w, off);
    }

    if (slot == 0) {
        float dv = dinv[v];
        float4 bv = bias4[q];
        out4[(size_t)v * 16 + q] = make_float4(fmaf(acc.x, dv, bv.x), fmaf(acc.y, dv, bv.y),
                                               fmaf(acc.z, dv, bv.z), fmaf(acc.w, dv, bv.w));
    }
}

// ---------------------------------------------------------------------------
// logits (r7-best, CSR): one wave/dst node; dst row loaded once; src gathered.
// ---------------------------------------------------------------------------
__global__ __launch_bounds__(256) void logits_csr_k(const int* __restrict__ rowptr,
                                                    const int* __restrict__ col,
                                                    const int* __restrict__ eid,
                                                    const float4* __restrict__ h4,
                                                    float* __restrict__ out, int N) {
    int v = (int)((blockIdx.x * (size_t)blockDim.x + threadIdx.x) >> 6);
    if (v >= N) return;
    int lane = threadIdx.x & 63;
    int q = lane & 15, slot = lane >> 4;
    int p0 = rowptr[v], p1 = rowptr[v + 1];
    if (p0 == p1) return;

    float4 rd = h4[(size_t)v * 16 + q];  // dst row (wave-resident)

    int p = p0;
    for (; p + 8 <= p1; p += 8) {
        int s0 = col[p + slot], s1 = col[p + 4 + slot];
        int e0 = eid[p + slot], e1 = eid[p + 4 + slot];
        float4 ra = h4[(size_t)s0 * 16 + q];
        float4 rb = h4[(size_t)s1 * 16 + q];
        float t0 = rd.x * ra.x + rd.y * ra.y + rd.z * ra.z + rd.w * ra.w;
        float t1 = rd.x * rb.x + rd.y * rb.y + rd.z * rb.z + rd.w * rb.w;
#pragma unroll
        for (int off = 1; off < 16; off <<= 1) {
            t0 += __shfl_xor(t0, off);
            t1 += __shfl_xor(t1, off);
        }
        if (q == 0) { out[e0] = t0; out[e1] = t1; }
    }
    for (; p + 4 <= p1; p += 4) {
        int s0 = col[p + slot];
        int e0 = eid[p + slot];
        float4 ra = h4[(size_t)s0 * 16 + q];
        float t0 = rd.x * ra.x + rd.y * ra.y + rd.z * ra.z + rd.w * ra.w;
#pragma unroll
        for (int off = 1; off < 16; off <<= 1) t0 += __shfl_xor(t0, off);
        if (q == 0) out[e0] = t0;
    }
    int rem = p1 - p;  // 0..3
    if (slot < rem) {
        int s0 = col[p + slot];
        int e0 = eid[p + slot];
        float4 ra = h4[(size_t)s0 * 16 + q];
        float t0 = rd.x * ra.x + rd.y * ra.y + rd.z * ra.z + rd.w * ra.w;
#pragma unroll
        for (int off = 1; off < 16; off <<= 1) t0 += __shfl_xor(t0, off);
        if (q == 0) out[e0] = t0;
    }
}

extern "C" void kernel_launch(void* const* d_in, const int* in_sizes, int n_in,
                              void* d_out, int out_size, void* d_ws, size_t ws_size,
                              hipStream_t stream) {
    const float* x  = (const float*)d_in[0];
    const int* ei   = (const int*)d_in[1];   // int32 (harness converts ints)
    const float* W1 = (const float*)d_in[2];
    const float* b1 = (const float*)d_in[3];
    const float* W2 = (const float*)d_in[4];
    const float* b2 = (const float*)d_in[5];
    float* out = (float*)d_out;

    const int N = in_sizes[0] / 128;   // 50000
    const int E = in_sizes[1] / 2;     // 800000
    const int* src = ei;
    const int* dst = ei + E;

    // ---- workspace ----
    // floats: dinv[50176] | bufA[N*128] | bufB[N*128]
    // ints:   cnt[N] | incl[N] | rowptr[N+1] | cursor[N] | bsum[256] | col[E] | eid[E]
    float* ws   = (float*)d_ws;
    float* dinv = ws;
    float* bufA = ws + 50176;
    float* bufB = bufA + (size_t)N * 128;
    float* hs1  = bufA;
    float* agg1 = bufB;
    float* g2s  = bufA;
    float* agg2 = bufA + (size_t)N * 64;

    int* ibase  = (int*)(bufB + (size_t)N * 128);
    int* cnt    = ibase;
    int* incl   = cnt + N;
    int* rowptr = incl + N;
    int* cursor = rowptr + (N + 1);
    int* bsum   = cursor + N;
    int* col    = bsum + 256;
    int* eid    = col + E;

    const int B = 256;
    const int NB = (N + 255) / 256;   // 196
    const unsigned nodeBlocks = (unsigned)(((size_t)N * 64 + 255) / 256);  // 12500

    // ---- CSR count + scan ----
    hipMemsetAsync(cnt, 0, (size_t)N * sizeof(int), stream);
    cnt_k<<<(E / 4 + B - 1) / B, B, 0, stream>>>(dst, cnt, E);
    scan1_k<<<NB, 256, 0, stream>>>(cnt, incl, bsum, N);
    scan23_k<<<NB, 256, 0, stream>>>(cnt, incl, bsum, rowptr, cursor, dinv, N, E, NB);

    // ---- fused, interleaved: GEMM1 (1564 blocks) + CSR fill (782 blocks) ----
    // grid 2346: g%3==2 -> fill block g/3 (0..781); else gemm block g-g/3 (0..1563)
    gemm1_fill_k<<<2346, 256, 0, stream>>>(x, W1, dinv, hs1, N,
                                           src, dst, cursor, col, eid, E);

    // ---- layer 1 pull ----
    pull128_k<<<nodeBlocks, 256, 0, stream>>>(rowptr, col, (const float4*)hs1, dinv,
                                              (const float4*)b1, (float4*)agg1, N);

    // ---- layer 2 ----
    gemm2_k<<<(N + 31) / 32, 256, 0, stream>>>(agg1, W2, dinv, g2s, N);
    pull64_k<<<nodeBlocks, 256, 0, stream>>>(rowptr, col, (const float4*)g2s, dinv,
                                             (const float4*)b2, (float4*)agg2, N);

    // ---- edge logits ----
    logits_csr_k<<<nodeBlocks, 256, 0, stream>>>(rowptr, col, eid, (const float4*)agg2, out, N);
}

// Round 13
// 238.380 us; speedup vs baseline: 1.1957x; 1.1957x over previous
//
#include <hip/hip_runtime.h>
#include <hip/hip_bf16.h>

// ---------------------------------------------------------------------------
// GCN 2-layer + edge dot logits, CSR-pull aggregation.
// agg[d] = dinv[d] * ( sum_{s in in(d)} hs[s] + hs[d] ) + b,  hs = (A@W)*dinv[row]
// Round 13: atomic-free CSR fill via rank[] captured in the count pass
// (pos = rowptr[dst] + rank); packed int2 {src,eid}; fill fused with GEMM1
// (range-split); BM=32 conflict-free GEMM; non-persistent pulls (r8-best).
// Pulls are at the ~3.6 TB/s L2-fill floor (FETCH ~= 7.3x table) - untouched.
// ---------------------------------------------------------------------------

// count + per-edge rank within its dst segment (atomic returns old count)
__global__ void cnt_rank_k(const int* __restrict__ dst, int* __restrict__ cnt,
                           int* __restrict__ rank, int E) {
    int t = blockIdx.x * blockDim.x + threadIdx.x;
    int e = t * 4;
    if (e + 4 <= E) {
        int4 d4 = *reinterpret_cast<const int4*>(dst + e);
        int4 r4;
        r4.x = atomicAdd(&cnt[d4.x], 1);
        r4.y = atomicAdd(&cnt[d4.y], 1);
        r4.z = atomicAdd(&cnt[d4.z], 1);
        r4.w = atomicAdd(&cnt[d4.w], 1);
        *reinterpret_cast<int4*>(rank + e) = r4;   // coalesced
    } else {
        for (int i = e; i < E; i++) rank[i] = atomicAdd(&cnt[dst[i]], 1);
    }
}

__global__ void scan1_k(const int* __restrict__ cnt, int* __restrict__ incl,
                        int* __restrict__ bsum, int N) {
    __shared__ int sh[256];
    int i = blockIdx.x * 256 + threadIdx.x;
    int v = (i < N) ? cnt[i] : 0;
    sh[threadIdx.x] = v;
    __syncthreads();
#pragma unroll
    for (int off = 1; off < 256; off <<= 1) {
        int t = (threadIdx.x >= off) ? sh[threadIdx.x - off] : 0;
        __syncthreads();
        sh[threadIdx.x] += t;
        __syncthreads();
    }
    if (i < N) incl[i] = sh[threadIdx.x];
    if (threadIdx.x == 255) bsum[blockIdx.x] = sh[255];
}

// fused scan2+scan3: every block rescans bsum in LDS, then writeback (+dinv).
__global__ __launch_bounds__(256) void scan23_k(const int* __restrict__ cnt,
                                                const int* __restrict__ incl,
                                                const int* __restrict__ bsum,
                                                int* __restrict__ rowptr,
                                                float* __restrict__ dinv,
                                                int N, int E, int NB) {
    __shared__ int sh[256];
    __shared__ int blockOff;
    int v = (threadIdx.x < NB) ? bsum[threadIdx.x] : 0;
    sh[threadIdx.x] = v;
    __syncthreads();
#pragma unroll
    for (int off = 1; off < 256; off <<= 1) {
        int t = (threadIdx.x >= off) ? sh[threadIdx.x - off] : 0;
        __syncthreads();
        sh[threadIdx.x] += t;
        __syncthreads();
    }
    if (threadIdx.x == blockIdx.x) blockOff = sh[threadIdx.x] - v;  // exclusive
    __syncthreads();
    int i = blockIdx.x * 256 + threadIdx.x;
    if (i < N) {
        int c = cnt[i];
        rowptr[i] = incl[i] - c + blockOff;
        dinv[i] = rsqrtf(1.0f + (float)c);  // +1 self-loop
    }
    if (i == 0) rowptr[N] = E;
}

// ---------------------------------------------------------------------------
// GEMM body, BM=32, BK=16, 256 threads (conflict-free LDS maps).
// ---------------------------------------------------------------------------
template <int BN, bool RELU>
__device__ __forceinline__ void gemm_body32(const float* __restrict__ A,
                                            const float* __restrict__ W,
                                            const float* __restrict__ dscale,
                                            float* __restrict__ Out, int M,
                                            int row0, float (*As)[36],
                                            float (*Bs)[BN]) {
    constexpr int K = 128, BK = 16;
    constexpr int TN = BN / 16;  // 8 (BN=128) or 4 (BN=64)
    const int tid = threadIdx.x;
    const int tx = tid & 15, ty = tid >> 4;

    float acc[2][TN];
#pragma unroll
    for (int m = 0; m < 2; m++)
#pragma unroll
        for (int n = 0; n < TN; n++) acc[m][n] = 0.0f;

    for (int kt = 0; kt < K; kt += BK) {
        if (tid < 128) {
            int r = tid >> 2;
            int kq = (tid & 3) * 4;
            float4 av = make_float4(0.f, 0.f, 0.f, 0.f);
            int gr = row0 + r;
            if (gr < M)
                av = *reinterpret_cast<const float4*>(A + (size_t)gr * K + kt + kq);
            if (RELU) {
                av.x = fmaxf(av.x, 0.f); av.y = fmaxf(av.y, 0.f);
                av.z = fmaxf(av.z, 0.f); av.w = fmaxf(av.w, 0.f);
            }
            As[kq + 0][r] = av.x; As[kq + 1][r] = av.y;
            As[kq + 2][r] = av.z; As[kq + 3][r] = av.w;
        }
#pragma unroll
        for (int s = 0; s < (BK * BN) / (256 * 4); s++) {
            int f = s * 256 + tid;
            int brow = f / (BN / 4);
            int bcol = (f % (BN / 4)) * 4;
            float4 bv = *reinterpret_cast<const float4*>(W + (size_t)(kt + brow) * BN + bcol);
            *reinterpret_cast<float4*>(&Bs[brow][bcol]) = bv;
        }
        __syncthreads();

#pragma unroll
        for (int k = 0; k < BK; k++) {
            float2 a2 = *reinterpret_cast<const float2*>(&As[k][ty * 2]);
            float a[2] = {a2.x, a2.y};
            float b[TN];
            float4 b0 = *reinterpret_cast<const float4*>(&Bs[k][tx * 4]);
            b[0] = b0.x; b[1] = b0.y; b[2] = b0.z; b[3] = b0.w;
            if (TN == 8) {
                float4 b1 = *reinterpret_cast<const float4*>(&Bs[k][64 + tx * 4]);
                b[4] = b1.x; b[5] = b1.y; b[6] = b1.z; b[7] = b1.w;
            }
#pragma unroll
            for (int m = 0; m < 2; m++)
#pragma unroll
                for (int n = 0; n < TN; n++) acc[m][n] = fmaf(a[m], b[n], acc[m][n]);
        }
        __syncthreads();
    }

#pragma unroll
    for (int m = 0; m < 2; m++) {
        int gr = row0 + ty * 2 + m;
        if (gr < M) {
            float dv = dscale[gr];
            float4 o0 = make_float4(acc[m][0] * dv, acc[m][1] * dv,
                                    acc[m][2] * dv, acc[m][3] * dv);
            *reinterpret_cast<float4*>(Out + (size_t)gr * BN + tx * 4) = o0;
            if (TN == 8) {
                float4 o1 = make_float4(acc[m][4] * dv, acc[m][5] * dv,
                                        acc[m][6] * dv, acc[m][7] * dv);
                *reinterpret_cast<float4*>(Out + (size_t)gr * BN + 64 + tx * 4) = o1;
            }
        }
    }
}

// ---------------------------------------------------------------------------
// FUSED (range-split): blocks [0,gemmBlocks) = GEMM1; rest = atomic-free CSR
// fill: pos = rowptr[dst] + rank  (rowptr gather is L2-hot 200KB).
// ---------------------------------------------------------------------------
__global__ __launch_bounds__(256) void gemm1_fill_k(const float* __restrict__ A,
                                                    const float* __restrict__ W,
                                                    const float* __restrict__ dscale,
                                                    float* __restrict__ Out, int M,
                                                    const int* __restrict__ src,
                                                    const int* __restrict__ dst,
                                                    const int* __restrict__ rowptr,
                                                    const int* __restrict__ rank,
                                                    int2* __restrict__ col2, int E,
                                                    int gemmBlocks) {
    __shared__ float As[16][36];
    __shared__ float Bs[16][128];
    int g = (int)blockIdx.x;
    if (g >= gemmBlocks) {
        int t = (g - gemmBlocks) * 256 + threadIdx.x;
        int e = t * 4;
        if (e + 4 <= E) {
            int4 s4 = *reinterpret_cast<const int4*>(src + e);
            int4 d4 = *reinterpret_cast<const int4*>(dst + e);
            int4 r4 = *reinterpret_cast<const int4*>(rank + e);
            col2[rowptr[d4.x] + r4.x] = make_int2(s4.x, e + 0);
            col2[rowptr[d4.y] + r4.y] = make_int2(s4.y, e + 1);
            col2[rowptr[d4.z] + r4.z] = make_int2(s4.z, e + 2);
            col2[rowptr[d4.w] + r4.w] = make_int2(s4.w, e + 3);
        } else {
            for (int i = e; i < E; i++)
                col2[rowptr[dst[i]] + rank[i]] = make_int2(src[i], i);
        }
        return;
    }
    gemm_body32<128, false>(A, W, dscale, Out, M, g * 32, As, Bs);
}

__global__ __launch_bounds__(256) void gemm2_k(const float* __restrict__ A,
                                               const float* __restrict__ W,
                                               const float* __restrict__ dscale,
                                               float* __restrict__ Out, int M) {
    __shared__ float As[16][36];
    __shared__ float Bs[16][64];
    gemm_body32<64, true>(A, W, dscale, Out, M, (int)blockIdx.x * 32, As, Bs);
}

// ---------------------------------------------------------------------------
// pull128: one wave/node, 2 slots x 32 lanes (row = 32 float4).
// ---------------------------------------------------------------------------
__global__ __launch_bounds__(256) void pull128_k(const int* __restrict__ rowptr,
                                                 const int2* __restrict__ col2,
                                                 const float4* __restrict__ hs4,
                                                 const float* __restrict__ dinv,
                                                 const float4* __restrict__ bias4,
                                                 float4* __restrict__ out4, int N) {
    int v = (int)((blockIdx.x * (size_t)blockDim.x + threadIdx.x) >> 6);
    if (v >= N) return;
    int lane = threadIdx.x & 63;
    int q = lane & 31, slot = lane >> 5;
    int p0 = rowptr[v], p1 = rowptr[v + 1];

    float4 acc = make_float4(0.f, 0.f, 0.f, 0.f);
    if (slot == 0) acc = hs4[(size_t)v * 32 + q];  // self row

    int p = p0;
    for (; p + 8 <= p1; p += 8) {
        int ia = col2[p + slot].x, ib = col2[p + 2 + slot].x;
        int ic = col2[p + 4 + slot].x, id = col2[p + 6 + slot].x;
        float4 a = hs4[(size_t)ia * 32 + q];
        float4 b = hs4[(size_t)ib * 32 + q];
        float4 c = hs4[(size_t)ic * 32 + q];
        float4 d = hs4[(size_t)id * 32 + q];
        acc.x += (a.x + b.x) + (c.x + d.x);
        acc.y += (a.y + b.y) + (c.y + d.y);
        acc.z += (a.z + b.z) + (c.z + d.z);
        acc.w += (a.w + b.w) + (c.w + d.w);
    }
    for (; p + 2 <= p1; p += 2) {
        int ia = col2[p + slot].x;
        float4 a = hs4[(size_t)ia * 32 + q];
        acc.x += a.x; acc.y += a.y; acc.z += a.z; acc.w += a.w;
    }
    if (p < p1 && slot == 0) {
        float4 a = hs4[(size_t)col2[p].x * 32 + q];
        acc.x += a.x; acc.y += a.y; acc.z += a.z; acc.w += a.w;
    }

    acc.x += __shfl_xor(acc.x, 32);
    acc.y += __shfl_xor(acc.y, 32);
    acc.z += __shfl_xor(acc.z, 32);
    acc.w += __shfl_xor(acc.w, 32);

    if (slot == 0) {
        float dv = dinv[v];
        float4 bv = bias4[q];
        out4[(size_t)v * 32 + q] = make_float4(fmaf(acc.x, dv, bv.x), fmaf(acc.y, dv, bv.y),
                                               fmaf(acc.z, dv, bv.z), fmaf(acc.w, dv, bv.w));
    }
}

// ---------------------------------------------------------------------------
// pull64: one wave/node, 4 slots x 16 lanes (row = 16 float4).
// ---------------------------------------------------------------------------
__global__ __launch_bounds__(256) void pull64_k(const int* __restrict__ rowptr,
                                                const int2* __restrict__ col2,
                                                const float4* __restrict__ hs4,
                                                const float* __restrict__ dinv,
                                                const float4* __restrict__ bias4,
                                                float4* __restrict__ out4, int N) {
    int v = (int)((blockIdx.x * (size_t)blockDim.x + threadIdx.x) >> 6);
    if (v >= N) return;
    int lane = threadIdx.x & 63;
    int q = lane & 15, slot = lane >> 4;
    int p0 = rowptr[v], p1 = rowptr[v + 1];

    float4 acc = make_float4(0.f, 0.f, 0.f, 0.f);
    if (slot == 0) acc = hs4[(size_t)v * 16 + q];  // self row

    int p = p0;
    for (; p + 8 <= p1; p += 8) {
        int ia = col2[p + slot].x, ib = col2[p + 4 + slot].x;
        float4 a = hs4[(size_t)ia * 16 + q];
        float4 b = hs4[(size_t)ib * 16 + q];
        acc.x += a.x + b.x; acc.y += a.y + b.y;
        acc.z += a.z + b.z; acc.w += a.w + b.w;
    }
    for (; p + 4 <= p1; p += 4) {
        float4 a = hs4[(size_t)col2[p + slot].x * 16 + q];
        acc.x += a.x; acc.y += a.y; acc.z += a.z; acc.w += a.w;
    }
    int rem = p1 - p;  // 0..3
    if (slot < rem) {
        float4 a = hs4[(size_t)col2[p + slot].x * 16 + q];
        acc.x += a.x; acc.y += a.y; acc.z += a.z; acc.w += a.w;
    }

#pragma unroll
    for (int off = 16; off <= 32; off <<= 1) {
        acc.x += __shfl_xor(acc.x, off);
        acc.y += __shfl_xor(acc.y, off);
        acc.z += __shfl_xor(acc.z, off);
        acc.w += __shfl_xor(acc.w, off);
    }

    if (slot == 0) {
        float dv = dinv[v];
        float4 bv = bias4[q];
        out4[(size_t)v * 16 + q] = make_float4(fmaf(acc.x, dv, bv.x), fmaf(acc.y, dv, bv.y),
                                               fmaf(acc.z, dv, bv.z), fmaf(acc.w, dv, bv.w));
    }
}

// ---------------------------------------------------------------------------
// logits via CSR: one wave/dst node; dst row loaded once; src rows gathered.
// col2 gives {src,eid} in one 8B load.
// ---------------------------------------------------------------------------
__global__ __launch_bounds__(256) void logits_csr_k(const int* __restrict__ rowptr,
                                                    const int2* __restrict__ col2,
                                                    const float4* __restrict__ h4,
                                                    float* __restrict__ out, int N) {
    int v = (int)((blockIdx.x * (size_t)blockDim.x + threadIdx.x) >> 6);
    if (v >= N) return;
    int lane = threadIdx.x & 63;
    int q = lane & 15, slot = lane >> 4;
    int p0 = rowptr[v], p1 = rowptr[v + 1];
    if (p0 == p1) return;

    float4 rd = h4[(size_t)v * 16 + q];  // dst row (wave-resident)

    int p = p0;
    for (; p + 8 <= p1; p += 8) {
        int2 ca = col2[p + slot], cb = col2[p + 4 + slot];
        float4 ra = h4[(size_t)ca.x * 16 + q];
        float4 rb = h4[(size_t)cb.x * 16 + q];
        float t0 = rd.x * ra.x + rd.y * ra.y + rd.z * ra.z + rd.w * ra.w;
        float t1 = rd.x * rb.x + rd.y * rb.y + rd.z * rb.z + rd.w * rb.w;
#pragma unroll
        for (int off = 1; off < 16; off <<= 1) {
            t0 += __shfl_xor(t0, off);
            t1 += __shfl_xor(t1, off);
        }
        if (q == 0) { out[ca.y] = t0; out[cb.y] = t1; }
    }
    for (; p + 4 <= p1; p += 4) {
        int2 ca = col2[p + slot];
        float4 ra = h4[(size_t)ca.x * 16 + q];
        float t0 = rd.x * ra.x + rd.y * ra.y + rd.z * ra.z + rd.w * ra.w;
#pragma unroll
        for (int off = 1; off < 16; off <<= 1) t0 += __shfl_xor(t0, off);
        if (q == 0) out[ca.y] = t0;
    }
    int rem = p1 - p;  // 0..3
    if (slot < rem) {
        int2 ca = col2[p + slot];
        float4 ra = h4[(size_t)ca.x * 16 + q];
        float t0 = rd.x * ra.x + rd.y * ra.y + rd.z * ra.z + rd.w * ra.w;
#pragma unroll
        for (int off = 1; off < 16; off <<= 1) t0 += __shfl_xor(t0, off);
        if (q == 0) out[ca.y] = t0;
    }
}

extern "C" void kernel_launch(void* const* d_in, const int* in_sizes, int n_in,
                              void* d_out, int out_size, void* d_ws, size_t ws_size,
                              hipStream_t stream) {
    const float* x  = (const float*)d_in[0];
    const int* ei   = (const int*)d_in[1];   // int32 (harness converts ints)
    const float* W1 = (const float*)d_in[2];
    const float* b1 = (const float*)d_in[3];
    const float* W2 = (const float*)d_in[4];
    const float* b2 = (const float*)d_in[5];
    float* out = (float*)d_out;

    const int N = in_sizes[0] / 128;   // 50000
    const int E = in_sizes[1] / 2;     // 800000
    const int* src = ei;
    const int* dst = ei + E;

    // ---- workspace ----
    // floats: dinv[50176] | bufA[N*128] | bufB[N*128]
    // ints:   cnt[N] | incl[N] | rowptr[N+2] | bsum[256] | rank[E] | col2[E] (int2)
    float* ws   = (float*)d_ws;
    float* dinv = ws;
    float* bufA = ws + 50176;
    float* bufB = bufA + (size_t)N * 128;
    float* hs1  = bufA;
    float* agg1 = bufB;
    float* g2s  = bufA;
    float* agg2 = bufA + (size_t)N * 64;

    int* ibase  = (int*)(bufB + (size_t)N * 128);
    int* cnt    = ibase;
    int* incl   = cnt + N;
    int* rowptr = incl + N;
    int* bsum   = rowptr + (N + 2);    // N+2 keeps later offsets even (int2 align)
    int* rank   = bsum + 256;
    int2* col2  = (int2*)(rank + E);

    const int B = 256;
    const int NB = (N + 255) / 256;   // 196
    const unsigned nodeBlocks = (unsigned)(((size_t)N * 64 + 255) / 256);  // 12500

    // ---- CSR count (+rank) + scan ----
    hipMemsetAsync(cnt, 0, (size_t)N * sizeof(int), stream);
    cnt_rank_k<<<(E / 4 + B - 1) / B, B, 0, stream>>>(dst, cnt, rank, E);
    scan1_k<<<NB, 256, 0, stream>>>(cnt, incl, bsum, N);
    scan23_k<<<NB, 256, 0, stream>>>(cnt, incl, bsum, rowptr, dinv, N, E, NB);

    // ---- fused (range-split): GEMM1 (1563 blocks) + atomic-free fill (782) ----
    {
        int gemmBlocks = (N + 31) / 32;              // 1563
        int fillBlocks = (E / 4 + B - 1) / B;        // 782
        gemm1_fill_k<<<gemmBlocks + fillBlocks, 256, 0, stream>>>(
            x, W1, dinv, hs1, N, src, dst, rowptr, rank, col2, E, gemmBlocks);
    }

    // ---- layer 1 pull ----
    pull128_k<<<nodeBlocks, 256, 0, stream>>>(rowptr, col2, (const float4*)hs1, dinv,
                                              (const float4*)b1, (float4*)agg1, N);

    // ---- layer 2 ----
    gemm2_k<<<(N + 31) / 32, 256, 0, stream>>>(agg1, W2, dinv, g2s, N);
    pull64_k<<<nodeBlocks, 256, 0, stream>>>(rowptr, col2, (const float4*)g2s, dinv,
                                             (const float4*)b2, (float4*)agg2, N);

    // ---- edge logits ----
    logits_csr_k<<<nodeBlocks, 256, 0, stream>>>(rowptr, col2, (const float4*)agg2, out, N);
}